// Round 14
// baseline (339.734 us; speedup 1.0000x reference)
//
#include <hip/hip_runtime.h>
#include <hip/hip_bf16.h>

#define N_ 256
#define S_ 128
#define H_ 512
#define E_ 256
#define O_ 32000
#define KZ 1792   // z row: 1024 ctx + 256 emb + 512 h
#define GJ 2048
#define KSPLIT 4
#define KCHUNK 448  // 14 steps of 32

#define PA_REP 6
#define PG_REP 12
#define PL_REP 20
#define PP_REP 6

typedef __attribute__((ext_vector_type(8))) short sv8;
typedef __attribute__((ext_vector_type(4))) float fv4;

__device__ __forceinline__ unsigned short f2bf(float f) {
  return __builtin_bit_cast(unsigned short, __float2bfloat16(f));
}

__device__ __forceinline__ sv8 pack8(fv4 a, fv4 b) {
  sv8 r;
  r[0] = (short)f2bf(a[0]); r[1] = (short)f2bf(a[1]);
  r[2] = (short)f2bf(a[2]); r[3] = (short)f2bf(a[3]);
  r[4] = (short)f2bf(b[0]); r[5] = (short)f2bf(b[1]);
  r[6] = (short)f2bf(b[2]); r[7] = (short)f2bf(b[3]);
  return r;
}

// ---------------- K1: full attention per n (16 waves x 8 s-rows, in-block combine)
__global__ __launch_bounds__(1024) void k_attn(
    const int* __restrict__ x, const float* __restrict__ eo,
    const float* __restrict__ hid, const float* __restrict__ emb,
    const float* __restrict__ We, const float* __restrict__ be,
    const float* __restrict__ Wih, const float* __restrict__ Whh,
    unsigned short* __restrict__ Wgbf, unsigned short* __restrict__ z)
{
  if (blockIdx.y == 1) {
    const int tid = blockIdx.x * 1024 + threadIdx.x;
    for (int g = tid; g < 2048 * 224; g += 256 * 1024) {
      const int j = g / 224, c = g - j * 224;
      sv8* dst = (sv8*)(Wgbf + (size_t)j * KZ);
      if (c < 160) {
        const fv4* src = (const fv4*)(Wih + (size_t)j * 1280);
        dst[c] = pack8(src[2 * c], src[2 * c + 1]);
      } else {
        const int cc = c - 160;
        const fv4* src = (const fv4*)(Whh + (size_t)j * 512);
        dst[c] = pack8(src[2 * cc], src[2 * cc + 1]);
      }
    }
    return;
  }

  const int n = blockIdx.x;
  const int t = threadIdx.x;
  const int w = t >> 6;
  const int l = t & 63;

  __shared__ float s_red[16];
  __shared__ float s_m[16], s_l[16];
  __shared__ float s_ctx[16][1024];

  float hv = (t < 512) ? hid[(size_t)n * H_ + t] * We[t] : 0.f;
  #pragma unroll
  for (int off = 32; off >= 1; off >>= 1) hv += __shfl_xor(hv, off);
  if (l == 0) s_red[w] = hv;
  __syncthreads();
  float hWe = be[0];
  #pragma unroll
  for (int i = 0; i < 8; ++i) hWe += s_red[i];

  fv4 we0, we1, we2, we3;
  {
    const fv4* wp = (const fv4*)(We + H_);
    we0 = wp[l]; we1 = wp[l + 64]; we2 = wp[l + 128]; we3 = wp[l + 192];
  }

  float m = 0.f, lsum = 0.f;
  fv4 c0 = {0,0,0,0}, c1 = {0,0,0,0}, c2 = {0,0,0,0}, c3 = {0,0,0,0};
  const float* eob = eo + ((size_t)n * S_ + w * 8) * 1024;
  #pragma unroll 2
  for (int i = 0; i < 8; ++i) {
    const fv4* p = (const fv4*)(eob + (size_t)i * 1024);
    fv4 v0 = p[l], v1 = p[l + 64], v2 = p[l + 128], v3 = p[l + 192];
    float d = 0.f;
    #pragma unroll
    for (int c = 0; c < 4; ++c)
      d += v0[c]*we0[c] + v1[c]*we1[c] + v2[c]*we2[c] + v3[c]*we3[c];
    #pragma unroll
    for (int off = 32; off >= 1; off >>= 1) d += __shfl_xor(d, off);
    const float e  = fmaxf(d + hWe, 0.f);
    const float mn = fmaxf(m, e);
    const float sc = __expf(m - mn);
    const float pp = __expf(e - mn);
    lsum = lsum * sc + pp;
    #pragma unroll
    for (int c = 0; c < 4; ++c) {
      c0[c] = c0[c]*sc + pp*v0[c];
      c1[c] = c1[c]*sc + pp*v1[c];
      c2[c] = c2[c]*sc + pp*v2[c];
      c3[c] = c3[c]*sc + pp*v3[c];
    }
    m = mn;
  }
  if (l == 0) { s_m[w] = m; s_l[w] = lsum; }
  {
    fv4* sc_ = (fv4*)s_ctx[w];
    sc_[l] = c0; sc_[l+64] = c1; sc_[l+128] = c2; sc_[l+192] = c3;
  }
  __syncthreads();

  float M = s_m[0];
  #pragma unroll
  for (int i = 1; i < 16; ++i) M = fmaxf(M, s_m[i]);
  float wgt[16]; float L = 0.f;
  #pragma unroll
  for (int i = 0; i < 16; ++i) { wgt[i] = __expf(s_m[i] - M); L += wgt[i] * s_l[i]; }
  const float rL = 1.f / L;

  float acc = 0.f;
  #pragma unroll
  for (int i = 0; i < 16; ++i) acc += wgt[i] * s_ctx[i][t];
  unsigned short* zr = z + (size_t)n * KZ;
  zr[t] = f2bf(acc * rL);

  if (t < 256)       zr[1024 + t] = f2bf(emb[(size_t)x[n] * E_ + t]);
  else if (t < 768)  zr[1024 + t] = f2bf(hid[(size_t)n * H_ + (t - 256)]);
}

// ---------------- K2: partial gates (bf16 MFMA, K-split 4)
__global__ __launch_bounds__(256) void k_gates(
    const unsigned short* __restrict__ z, const unsigned short* __restrict__ Wgbf,
    float* __restrict__ part)
{
  const int j0 = blockIdx.x * 64;
  const int n0 = blockIdx.y * 64;
  const int kc = blockIdx.z * KCHUNK;
  const int t = threadIdx.x;
  const int w = t >> 6, l = t & 63;
  const int lr = l & 15, lg = l >> 4;
  const int jb = j0 + w * 16 + lr;

  const unsigned short* arow = z + kc + 8 * lg;
  const unsigned short* wrow = Wgbf + (size_t)jb * KZ + kc + 8 * lg;

  fv4 acc[4] = {{0,0,0,0},{0,0,0,0},{0,0,0,0},{0,0,0,0}};
  #pragma unroll
  for (int s = 0; s < 14; ++s) {
    const sv8 bf = *(const sv8*)(wrow + s * 32);
    #pragma unroll
    for (int f = 0; f < 4; ++f) {
      const sv8 af = *(const sv8*)(arow + (size_t)(n0 + f*16 + lr) * KZ + s * 32);
      acc[f] = __builtin_amdgcn_mfma_f32_16x16x32_bf16(af, bf, acc[f], 0, 0, 0);
    }
  }
  float* pp = part + (size_t)blockIdx.z * (N_ * GJ);
  #pragma unroll
  for (int f = 0; f < 4; ++f) {
    #pragma unroll
    for (int r = 0; r < 4; ++r)
      pp[(size_t)(n0 + f*16 + lg*4 + r) * GJ + jb] = acc[f][r];
  }
}

// ---------------- K3: LSTM cell elementwise
__global__ __launch_bounds__(256) void k_lstm(
    const float* __restrict__ part, const float* __restrict__ cell,
    const float* __restrict__ bih, const float* __restrict__ bhh,
    float* __restrict__ hout, float* __restrict__ cout,
    unsigned short* __restrict__ hbf)
{
  const int tid = blockIdx.x * 256 + threadIdx.x;
  const int n = tid >> 9, hh = tid & 511;
  const size_t base = (size_t)n * GJ;
  float ig = bih[hh]        + bhh[hh];
  float fg = bih[512 + hh]  + bhh[512 + hh];
  float gg = bih[1024 + hh] + bhh[1024 + hh];
  float og = bih[1536 + hh] + bhh[1536 + hh];
  #pragma unroll
  for (int k = 0; k < KSPLIT; ++k) {
    const float* p = part + (size_t)k * (N_ * GJ) + base;
    ig += p[hh];
    fg += p[512 + hh];
    gg += p[1024 + hh];
    og += p[1536 + hh];
  }
  ig = 1.f / (1.f + __expf(-ig));
  fg = 1.f / (1.f + __expf(-fg));
  og = 1.f / (1.f + __expf(-og));
  gg = tanhf(gg);
  const float c = fg * cell[tid] + ig * gg;
  const float h = og * tanhf(c);
  cout[tid] = c;
  hout[tid] = h;
  hbf[tid] = f2bf(h);
}

// ---------------- K4: predictions (LDS-staged bf16 MFMA)
__global__ __launch_bounds__(512, 2) void k_pred(
    const unsigned short* __restrict__ hbf, const float* __restrict__ Wout,
    const float* __restrict__ bout, float* __restrict__ pred)
{
  __shared__ unsigned short Blds[64 * 512];
  const int o0 = blockIdx.x * 64;
  const int t = threadIdx.x;

  #pragma unroll
  for (int i = 0; i < 8; ++i) {
    const int g = t + i * 512;
    const int row = g >> 6, c = g & 63;
    const fv4* src = (const fv4*)(Wout + (size_t)(o0 + row) * H_ + c * 8);
    const sv8 v = pack8(src[0], src[1]);
    *(sv8*)((char*)Blds + row * 1024 + ((c * 16) ^ ((row & 7) << 4))) = v;
  }
  __syncthreads();

  const int w = t >> 6, l = t & 63;
  const int lr = l & 15, lg = l >> 4;
  const int nr = w * 32;

  fv4 acc[2][4] = {};
  #pragma unroll
  for (int kk = 0; kk < 16; ++kk) {
    sv8 a[2];
    #pragma unroll
    for (int f = 0; f < 2; ++f)
      a[f] = *(const sv8*)(hbf + (size_t)(nr + f*16 + lr) * H_ + kk*32 + 8*lg);
    #pragma unroll
    for (int fo = 0; fo < 4; ++fo) {
      const int row = fo * 16 + lr;
      const sv8 b = *(const sv8*)((const char*)Blds + row * 1024 +
                                  ((kk*64 + lg*16) ^ ((row & 7) << 4)));
      #pragma unroll
      for (int f = 0; f < 2; ++f)
        acc[f][fo] = __builtin_amdgcn_mfma_f32_16x16x32_bf16(a[f], b, acc[f][fo], 0, 0, 0);
    }
  }
  #pragma unroll
  for (int fo = 0; fo < 4; ++fo) {
    const int oo = o0 + fo*16 + lr;
    const float bo = bout[oo];
    #pragma unroll
    for (int f = 0; f < 2; ++f) {
      #pragma unroll
      for (int r = 0; r < 4; ++r)
        pred[(size_t)(nr + f*16 + lg*4 + r) * O_ + oo] = acc[f][fo][r] + bo;
    }
  }
}

// ================= PROBES (diagnostic only; write scratch; run after pipeline)

// attn body x PA_REP -> zp
__global__ __launch_bounds__(1024) void p_attn(
    const float* __restrict__ eo, const float* __restrict__ hid,
    const float* __restrict__ We, const float* __restrict__ be,
    unsigned short* __restrict__ zp)
{
  const int n = blockIdx.x;
  const int t = threadIdx.x;
  const int w = t >> 6;
  const int l = t & 63;

  __shared__ float s_red[16];
  __shared__ float s_m[16], s_l[16];
  __shared__ float s_ctx[16][1024];

  for (int rep = 0; rep < PA_REP; ++rep) {
    float hv = (t < 512) ? hid[(size_t)n * H_ + t] * We[t] : 0.f;
    #pragma unroll
    for (int off = 32; off >= 1; off >>= 1) hv += __shfl_xor(hv, off);
    if (l == 0) s_red[w] = hv;
    __syncthreads();
    float hWe = be[0];
    #pragma unroll
    for (int i = 0; i < 8; ++i) hWe += s_red[i];

    fv4 we0, we1, we2, we3;
    {
      const fv4* wp = (const fv4*)(We + H_);
      we0 = wp[l]; we1 = wp[l + 64]; we2 = wp[l + 128]; we3 = wp[l + 192];
    }

    float m = 0.f, lsum = 0.f;
    fv4 c0 = {0,0,0,0}, c1 = {0,0,0,0}, c2 = {0,0,0,0}, c3 = {0,0,0,0};
    const float* eob = eo + ((size_t)n * S_ + w * 8) * 1024;
    #pragma unroll 2
    for (int i = 0; i < 8; ++i) {
      const fv4* p = (const fv4*)(eob + (size_t)i * 1024);
      fv4 v0 = p[l], v1 = p[l + 64], v2 = p[l + 128], v3 = p[l + 192];
      float d = 0.f;
      #pragma unroll
      for (int c = 0; c < 4; ++c)
        d += v0[c]*we0[c] + v1[c]*we1[c] + v2[c]*we2[c] + v3[c]*we3[c];
      #pragma unroll
      for (int off = 32; off >= 1; off >>= 1) d += __shfl_xor(d, off);
      const float e  = fmaxf(d + hWe, 0.f);
      const float mn = fmaxf(m, e);
      const float sc = __expf(m - mn);
      const float pp = __expf(e - mn);
      lsum = lsum * sc + pp;
      #pragma unroll
      for (int c = 0; c < 4; ++c) {
        c0[c] = c0[c]*sc + pp*v0[c];
        c1[c] = c1[c]*sc + pp*v1[c];
        c2[c] = c2[c]*sc + pp*v2[c];
        c3[c] = c3[c]*sc + pp*v3[c];
      }
      m = mn;
    }
    if (l == 0) { s_m[w] = m; s_l[w] = lsum; }
    {
      fv4* sc_ = (fv4*)s_ctx[w];
      sc_[l] = c0; sc_[l+64] = c1; sc_[l+128] = c2; sc_[l+192] = c3;
    }
    __syncthreads();

    float M = s_m[0];
    #pragma unroll
    for (int i = 1; i < 16; ++i) M = fmaxf(M, s_m[i]);
    float wgt[16]; float L = 0.f;
    #pragma unroll
    for (int i = 0; i < 16; ++i) { wgt[i] = __expf(s_m[i] - M); L += wgt[i] * s_l[i]; }
    const float rL = 1.f / L;

    float acc = 0.f;
    #pragma unroll
    for (int i = 0; i < 16; ++i) acc += wgt[i] * s_ctx[i][t];
    zp[(size_t)n * KZ + t] = f2bf(acc * rL);
    __syncthreads();
  }
}

// gates body x PG_REP -> partp
__global__ __launch_bounds__(256) void p_gates(
    const unsigned short* __restrict__ z, const unsigned short* __restrict__ Wgbf,
    float* __restrict__ partp)
{
  const int j0 = blockIdx.x * 64;
  const int n0 = blockIdx.y * 64;
  const int kc = blockIdx.z * KCHUNK;
  const int t = threadIdx.x;
  const int w = t >> 6, l = t & 63;
  const int lr = l & 15, lg = l >> 4;
  const int jb = j0 + w * 16 + lr;

  const unsigned short* arow = z + kc + 8 * lg;
  const unsigned short* wrow = Wgbf + (size_t)jb * KZ + kc + 8 * lg;

  for (int rep = 0; rep < PG_REP; ++rep) {
    fv4 acc[4] = {{0,0,0,0},{0,0,0,0},{0,0,0,0},{0,0,0,0}};
    #pragma unroll
    for (int s = 0; s < 14; ++s) {
      const sv8 bf = *(const sv8*)(wrow + s * 32);
      #pragma unroll
      for (int f = 0; f < 4; ++f) {
        const sv8 af = *(const sv8*)(arow + (size_t)(n0 + f*16 + lr) * KZ + s * 32);
        acc[f] = __builtin_amdgcn_mfma_f32_16x16x32_bf16(af, bf, acc[f], 0, 0, 0);
      }
    }
    float* pp = partp + (size_t)blockIdx.z * (N_ * GJ);
    #pragma unroll
    for (int f = 0; f < 4; ++f) {
      #pragma unroll
      for (int r = 0; r < 4; ++r)
        pp[(size_t)(n0 + f*16 + lg*4 + r) * GJ + jb] = acc[f][r];
    }
  }
}

// lstm body x PL_REP -> lstmp scratch
__global__ __launch_bounds__(256) void p_lstm(
    const float* __restrict__ part, const float* __restrict__ cell,
    const float* __restrict__ bih, const float* __restrict__ bhh,
    float* __restrict__ houtp, float* __restrict__ coutp,
    unsigned short* __restrict__ hbfp)
{
  const int tid = blockIdx.x * 256 + threadIdx.x;
  const int n = tid >> 9, hh = tid & 511;
  const size_t base = (size_t)n * GJ;
  for (int rep = 0; rep < PL_REP; ++rep) {
    float ig = bih[hh]        + bhh[hh];
    float fg = bih[512 + hh]  + bhh[512 + hh];
    float gg = bih[1024 + hh] + bhh[1024 + hh];
    float og = bih[1536 + hh] + bhh[1536 + hh];
    #pragma unroll
    for (int k = 0; k < KSPLIT; ++k) {
      const float* p = part + (size_t)k * (N_ * GJ) + base;
      ig += p[hh];
      fg += p[512 + hh];
      gg += p[1024 + hh];
      og += p[1536 + hh];
    }
    ig = 1.f / (1.f + __expf(-ig));
    fg = 1.f / (1.f + __expf(-fg));
    og = 1.f / (1.f + __expf(-og));
    gg = tanhf(gg);
    const float c = fg * cell[tid] + ig * gg;
    const float h = og * tanhf(c);
    coutp[tid] = c;
    houtp[tid] = h;
    hbfp[tid] = f2bf(h);
  }
}

// pred body x PP_REP -> predp
__global__ __launch_bounds__(512, 2) void p_pred(
    const unsigned short* __restrict__ hbf, const float* __restrict__ Wout,
    const float* __restrict__ bout, float* __restrict__ predp)
{
  __shared__ unsigned short Blds[64 * 512];
  const int o0 = blockIdx.x * 64;
  const int t = threadIdx.x;
  const int w = t >> 6, l = t & 63;
  const int lr = l & 15, lg = l >> 4;
  const int nr = w * 32;

  for (int rep = 0; rep < PP_REP; ++rep) {
    __syncthreads();
    #pragma unroll
    for (int i = 0; i < 8; ++i) {
      const int g = t + i * 512;
      const int row = g >> 6, c = g & 63;
      const fv4* src = (const fv4*)(Wout + (size_t)(o0 + row) * H_ + c * 8);
      const sv8 v = pack8(src[0], src[1]);
      *(sv8*)((char*)Blds + row * 1024 + ((c * 16) ^ ((row & 7) << 4))) = v;
    }
    __syncthreads();

    fv4 acc[2][4] = {};
    #pragma unroll
    for (int kk = 0; kk < 16; ++kk) {
      sv8 a[2];
      #pragma unroll
      for (int f = 0; f < 2; ++f)
        a[f] = *(const sv8*)(hbf + (size_t)(nr + f*16 + lr) * H_ + kk*32 + 8*lg);
      #pragma unroll
      for (int fo = 0; fo < 4; ++fo) {
        const int row = fo * 16 + lr;
        const sv8 b = *(const sv8*)((const char*)Blds + row * 1024 +
                                    ((kk*64 + lg*16) ^ ((row & 7) << 4)));
        #pragma unroll
        for (int f = 0; f < 2; ++f)
          acc[f][fo] = __builtin_amdgcn_mfma_f32_16x16x32_bf16(a[f], b, acc[f][fo], 0, 0, 0);
      }
    }
    #pragma unroll
    for (int fo = 0; fo < 4; ++fo) {
      const int oo = o0 + fo*16 + lr;
      const float bo = bout[oo];
      #pragma unroll
      for (int f = 0; f < 2; ++f) {
        #pragma unroll
        for (int r = 0; r < 4; ++r)
          predp[(size_t)(nr + f*16 + lg*4 + r) * O_ + oo] = acc[f][fo][r] + bo;
      }
    }
  }
}

extern "C" void kernel_launch(void* const* d_in, const int* in_sizes, int n_in,
                              void* d_out, int out_size, void* d_ws, size_t ws_size,
                              hipStream_t stream) {
  const int*   x    = (const int*)  d_in[0];
  const float* eo   = (const float*)d_in[1];
  const float* hid  = (const float*)d_in[2];
  const float* cell = (const float*)d_in[3];
  const float* emb  = (const float*)d_in[4];
  const float* We   = (const float*)d_in[5];
  const float* be   = (const float*)d_in[6];
  const float* Wih  = (const float*)d_in[7];
  const float* Whh  = (const float*)d_in[8];
  const float* bih  = (const float*)d_in[9];
  const float* bhh  = (const float*)d_in[10];
  const float* Wout = (const float*)d_in[11];
  const float* bout = (const float*)d_in[12];

  float* pred = (float*)d_out;
  float* hout = pred + (size_t)N_ * O_;
  float* cout = hout + (size_t)N_ * H_;

  unsigned short* z    = (unsigned short*)d_ws;                    // 0.92 MB
  unsigned short* hbf  = z + (size_t)N_ * KZ;                      // 0.26 MB
  float* part = (float*)(hbf + (size_t)N_ * H_);                   // 8 MB
  unsigned short* Wgbf = (unsigned short*)(part + (size_t)KSPLIT * N_ * GJ);  // 7.34 MB
  // probe scratch
  unsigned short* zp   = Wgbf + (size_t)GJ * KZ;                   // 0.92 MB
  float* partp = (float*)(zp + (size_t)N_ * KZ);                   // 8 MB
  float* predp = partp + (size_t)KSPLIT * N_ * GJ;                 // 32.8 MB
  float* houtp = predp + (size_t)N_ * O_;                          // 0.5 MB
  float* coutp = houtp + (size_t)N_ * H_;
  unsigned short* hbfp = (unsigned short*)(coutp + (size_t)N_ * H_);

  // real pipeline (R8, best known)
  k_attn <<<dim3(256, 2), 1024, 0, stream>>>(x, eo, hid, emb, We, be,
                                             Wih, Whh, Wgbf, z);
  k_gates<<<dim3(32, 4, KSPLIT), 256, 0, stream>>>(z, Wgbf, part);
  k_lstm <<<512, 256, 0, stream>>>(part, cell, bih, bhh, hout, cout, hbf);
  k_pred <<<500, 512, 0, stream>>>(hbf, Wout, bout, pred);

  // diagnostic probes (scratch-only, deterministic)
  p_attn <<<256, 1024, 0, stream>>>(eo, hid, We, be, zp);
  p_gates<<<dim3(32, 4, KSPLIT), 256, 0, stream>>>(z, Wgbf, partp);
  p_lstm <<<512, 256, 0, stream>>>(part, cell, bih, bhh, houtp, coutp, hbfp);
  p_pred <<<500, 512, 0, stream>>>(hbf, Wout, bout, predp);
}

// Round 15
// 84.066 us; speedup vs baseline: 4.0413x; 4.0413x over previous
//
#include <hip/hip_runtime.h>
#include <hip/hip_bf16.h>

#define N_ 256
#define S_ 128
#define H_ 512
#define E_ 256
#define O_ 32000
#define KZ 1792   // z row: 1024 ctx + 256 emb + 512 h
#define GJ 2048
#define KSPLIT 4
#define KCHUNK 448  // 14 steps of 32

typedef __attribute__((ext_vector_type(8))) short sv8;
typedef __attribute__((ext_vector_type(4))) float fv4;

__device__ __forceinline__ unsigned short f2bf(float f) {
  return __builtin_bit_cast(unsigned short, __float2bfloat16(f));
}

__device__ __forceinline__ sv8 pack8(fv4 a, fv4 b) {
  sv8 r;
  r[0] = (short)f2bf(a[0]); r[1] = (short)f2bf(a[1]);
  r[2] = (short)f2bf(a[2]); r[3] = (short)f2bf(a[3]);
  r[4] = (short)f2bf(b[0]); r[5] = (short)f2bf(b[1]);
  r[6] = (short)f2bf(b[2]); r[7] = (short)f2bf(b[3]);
  return r;
}

// ---------------- K1: full attention per n (16 waves x 8 s-rows, in-block combine)
__global__ __launch_bounds__(1024) void k_attn(
    const int* __restrict__ x, const float* __restrict__ eo,
    const float* __restrict__ hid, const float* __restrict__ emb,
    const float* __restrict__ We, const float* __restrict__ be,
    const float* __restrict__ Wih, const float* __restrict__ Whh,
    unsigned short* __restrict__ Wgbf, unsigned short* __restrict__ z)
{
  if (blockIdx.y == 1) {
    const int tid = blockIdx.x * 1024 + threadIdx.x;
    for (int g = tid; g < 2048 * 224; g += 256 * 1024) {
      const int j = g / 224, c = g - j * 224;
      sv8* dst = (sv8*)(Wgbf + (size_t)j * KZ);
      if (c < 160) {
        const fv4* src = (const fv4*)(Wih + (size_t)j * 1280);
        dst[c] = pack8(src[2 * c], src[2 * c + 1]);
      } else {
        const int cc = c - 160;
        const fv4* src = (const fv4*)(Whh + (size_t)j * 512);
        dst[c] = pack8(src[2 * cc], src[2 * cc + 1]);
      }
    }
    return;
  }

  const int n = blockIdx.x;
  const int t = threadIdx.x;
  const int w = t >> 6;
  const int l = t & 63;

  __shared__ float s_red[16];
  __shared__ float s_m[16], s_l[16];
  __shared__ float s_ctx[16][1024];

  float hv = (t < 512) ? hid[(size_t)n * H_ + t] * We[t] : 0.f;
  #pragma unroll
  for (int off = 32; off >= 1; off >>= 1) hv += __shfl_xor(hv, off);
  if (l == 0) s_red[w] = hv;
  __syncthreads();
  float hWe = be[0];
  #pragma unroll
  for (int i = 0; i < 8; ++i) hWe += s_red[i];

  fv4 we0, we1, we2, we3;
  {
    const fv4* wp = (const fv4*)(We + H_);
    we0 = wp[l]; we1 = wp[l + 64]; we2 = wp[l + 128]; we3 = wp[l + 192];
  }

  float m = 0.f, lsum = 0.f;
  fv4 c0 = {0,0,0,0}, c1 = {0,0,0,0}, c2 = {0,0,0,0}, c3 = {0,0,0,0};
  const float* eob = eo + ((size_t)n * S_ + w * 8) * 1024;
  #pragma unroll 2
  for (int i = 0; i < 8; ++i) {
    const fv4* p = (const fv4*)(eob + (size_t)i * 1024);
    fv4 v0 = p[l], v1 = p[l + 64], v2 = p[l + 128], v3 = p[l + 192];
    float d = 0.f;
    #pragma unroll
    for (int c = 0; c < 4; ++c)
      d += v0[c]*we0[c] + v1[c]*we1[c] + v2[c]*we2[c] + v3[c]*we3[c];
    #pragma unroll
    for (int off = 32; off >= 1; off >>= 1) d += __shfl_xor(d, off);
    const float e  = fmaxf(d + hWe, 0.f);
    const float mn = fmaxf(m, e);
    const float sc = __expf(m - mn);
    const float pp = __expf(e - mn);
    lsum = lsum * sc + pp;
    #pragma unroll
    for (int c = 0; c < 4; ++c) {
      c0[c] = c0[c]*sc + pp*v0[c];
      c1[c] = c1[c]*sc + pp*v1[c];
      c2[c] = c2[c]*sc + pp*v2[c];
      c3[c] = c3[c]*sc + pp*v3[c];
    }
    m = mn;
  }
  if (l == 0) { s_m[w] = m; s_l[w] = lsum; }
  {
    fv4* sc_ = (fv4*)s_ctx[w];
    sc_[l] = c0; sc_[l+64] = c1; sc_[l+128] = c2; sc_[l+192] = c3;
  }
  __syncthreads();

  float M = s_m[0];
  #pragma unroll
  for (int i = 1; i < 16; ++i) M = fmaxf(M, s_m[i]);
  float wgt[16]; float L = 0.f;
  #pragma unroll
  for (int i = 0; i < 16; ++i) { wgt[i] = __expf(s_m[i] - M); L += wgt[i] * s_l[i]; }
  const float rL = 1.f / L;

  float acc = 0.f;
  #pragma unroll
  for (int i = 0; i < 16; ++i) acc += wgt[i] * s_ctx[i][t];
  unsigned short* zr = z + (size_t)n * KZ;
  zr[t] = f2bf(acc * rL);

  if (t < 256)       zr[1024 + t] = f2bf(emb[(size_t)x[n] * E_ + t]);
  else if (t < 768)  zr[1024 + t] = f2bf(hid[(size_t)n * H_ + (t - 256)]);
}

// ---------------- K2: partial gates (bf16 MFMA, K-split 4)
__global__ __launch_bounds__(256) void k_gates(
    const unsigned short* __restrict__ z, const unsigned short* __restrict__ Wgbf,
    float* __restrict__ part)
{
  const int j0 = blockIdx.x * 64;
  const int n0 = blockIdx.y * 64;
  const int kc = blockIdx.z * KCHUNK;
  const int t = threadIdx.x;
  const int w = t >> 6, l = t & 63;
  const int lr = l & 15, lg = l >> 4;
  const int jb = j0 + w * 16 + lr;

  const unsigned short* arow = z + kc + 8 * lg;
  const unsigned short* wrow = Wgbf + (size_t)jb * KZ + kc + 8 * lg;

  fv4 acc[4] = {{0,0,0,0},{0,0,0,0},{0,0,0,0},{0,0,0,0}};
  #pragma unroll
  for (int s = 0; s < 14; ++s) {
    const sv8 bf = *(const sv8*)(wrow + s * 32);
    #pragma unroll
    for (int f = 0; f < 4; ++f) {
      const sv8 af = *(const sv8*)(arow + (size_t)(n0 + f*16 + lr) * KZ + s * 32);
      acc[f] = __builtin_amdgcn_mfma_f32_16x16x32_bf16(af, bf, acc[f], 0, 0, 0);
    }
  }
  float* pp = part + (size_t)blockIdx.z * (N_ * GJ);
  #pragma unroll
  for (int f = 0; f < 4; ++f) {
    #pragma unroll
    for (int r = 0; r < 4; ++r)
      pp[(size_t)(n0 + f*16 + lg*4 + r) * GJ + jb] = acc[f][r];
  }
}

// ---------------- K3: LSTM cell elementwise
__global__ __launch_bounds__(256) void k_lstm(
    const float* __restrict__ part, const float* __restrict__ cell,
    const float* __restrict__ bih, const float* __restrict__ bhh,
    float* __restrict__ hout, float* __restrict__ cout,
    unsigned short* __restrict__ hbf)
{
  const int tid = blockIdx.x * 256 + threadIdx.x;
  const int n = tid >> 9, hh = tid & 511;
  const size_t base = (size_t)n * GJ;
  float ig = bih[hh]        + bhh[hh];
  float fg = bih[512 + hh]  + bhh[512 + hh];
  float gg = bih[1024 + hh] + bhh[1024 + hh];
  float og = bih[1536 + hh] + bhh[1536 + hh];
  #pragma unroll
  for (int k = 0; k < KSPLIT; ++k) {
    const float* p = part + (size_t)k * (N_ * GJ) + base;
    ig += p[hh];
    fg += p[512 + hh];
    gg += p[1024 + hh];
    og += p[1536 + hh];
  }
  ig = 1.f / (1.f + __expf(-ig));
  fg = 1.f / (1.f + __expf(-fg));
  og = 1.f / (1.f + __expf(-og));
  gg = tanhf(gg);
  const float c = fg * cell[tid] + ig * gg;
  const float h = og * tanhf(c);
  cout[tid] = c;
  hout[tid] = h;
  hbf[tid] = f2bf(h);
}

// ---------------- K4: predictions = h_new @ W_out^T + b_out
// SWAPPED-OPERAND MFMA: acc = mfma(b_wout, a_h) computes the transposed tile,
// so each lane's 4 acc regs are 4 CONSECUTIVE o-columns of one pred row ->
// float4 stores (4x fewer store instrs, 16B/lane) — R14 probe showed k_pred
// is write-path-bound (VALUBusy 0.4%, WRITE inflated 33->45MB).
__global__ __launch_bounds__(512, 2) void k_pred(
    const unsigned short* __restrict__ hbf, const float* __restrict__ Wout,
    const float* __restrict__ bout, float* __restrict__ pred)
{
  __shared__ unsigned short Blds[64 * 512];   // 64 KB, row = o-col, 1024 B/row
  const int o0 = blockIdx.x * 64;
  const int t = threadIdx.x;

  #pragma unroll
  for (int i = 0; i < 8; ++i) {
    const int g = t + i * 512;
    const int row = g >> 6, c = g & 63;
    const fv4* src = (const fv4*)(Wout + (size_t)(o0 + row) * H_ + c * 8);
    const sv8 v = pack8(src[0], src[1]);
    *(sv8*)((char*)Blds + row * 1024 + ((c * 16) ^ ((row & 7) << 4))) = v;
  }
  __syncthreads();

  const int w = t >> 6, l = t & 63;
  const int lr = l & 15, lg = l >> 4;
  const int nr = w * 32;   // wave handles 32 n-rows x 64 o-cols

  fv4 acc[2][4] = {};
  #pragma unroll
  for (int kk = 0; kk < 16; ++kk) {
    sv8 a[2];
    #pragma unroll
    for (int f = 0; f < 2; ++f)
      a[f] = *(const sv8*)(hbf + (size_t)(nr + f*16 + lr) * H_ + kk*32 + 8*lg);
    #pragma unroll
    for (int fo = 0; fo < 4; ++fo) {
      const int row = fo * 16 + lr;
      const sv8 b = *(const sv8*)((const char*)Blds + row * 1024 +
                                  ((kk*64 + lg*16) ^ ((row & 7) << 4)));
      #pragma unroll
      for (int f = 0; f < 2; ++f)
        acc[f][fo] = __builtin_amdgcn_mfma_f32_16x16x32_bf16(b, a[f], acc[f][fo], 0, 0, 0);
    }
  }
  // lane holds D[o = o0+fo*16+lg*4+r][n = nr+f*16+lr], r=0..3 consecutive o
  #pragma unroll
  for (int fo = 0; fo < 4; ++fo) {
    const int ob = o0 + fo * 16 + lg * 4;
    const fv4 bo4 = *(const fv4*)(bout + ob);
    #pragma unroll
    for (int f = 0; f < 2; ++f) {
      const int n = nr + f * 16 + lr;
      fv4 v;
      #pragma unroll
      for (int r = 0; r < 4; ++r) v[r] = acc[f][fo][r] + bo4[r];
      *(fv4*)(pred + (size_t)n * O_ + ob) = v;
    }
  }
}

extern "C" void kernel_launch(void* const* d_in, const int* in_sizes, int n_in,
                              void* d_out, int out_size, void* d_ws, size_t ws_size,
                              hipStream_t stream) {
  const int*   x    = (const int*)  d_in[0];
  const float* eo   = (const float*)d_in[1];
  const float* hid  = (const float*)d_in[2];
  const float* cell = (const float*)d_in[3];
  const float* emb  = (const float*)d_in[4];
  const float* We   = (const float*)d_in[5];
  const float* be   = (const float*)d_in[6];
  const float* Wih  = (const float*)d_in[7];
  const float* Whh  = (const float*)d_in[8];
  const float* bih  = (const float*)d_in[9];
  const float* bhh  = (const float*)d_in[10];
  const float* Wout = (const float*)d_in[11];
  const float* bout = (const float*)d_in[12];

  float* pred = (float*)d_out;
  float* hout = pred + (size_t)N_ * O_;
  float* cout = hout + (size_t)N_ * H_;

  unsigned short* z    = (unsigned short*)d_ws;           // 917504 B
  unsigned short* hbf  = z + (size_t)N_ * KZ;             // 262144 B
  float* part = (float*)(hbf + (size_t)N_ * H_);          // 8 MB
  unsigned short* Wgbf = (unsigned short*)(part + (size_t)KSPLIT * N_ * GJ);  // 7.34 MB

  k_attn <<<dim3(256, 2), 1024, 0, stream>>>(x, eo, hid, emb, We, be,
                                             Wih, Whh, Wgbf, z);
  k_gates<<<dim3(32, 4, KSPLIT), 256, 0, stream>>>(z, Wgbf, part);
  k_lstm <<<512, 256, 0, stream>>>(part, cell, bih, bhh, hout, cout, hbf);
  k_pred <<<500, 512, 0, stream>>>(hbf, Wout, bout, pred);
}